// Round 6
// baseline (4030.257 us; speedup 1.0000x reference)
//
#include <hip/hip_runtime.h>
#include <math.h>

// Problem constants (TransformerController)
#define B_  32
#define S_  512
#define T_  180
#define D_  512
#define F_  2048
#define L_  6
#define H_  8
#define DH_ 64

typedef unsigned short u16;
typedef __attribute__((ext_vector_type(8))) short short8;   // 8 x bf16
typedef __attribute__((ext_vector_type(4))) float floatx4;  // MFMA acc

__device__ __forceinline__ float bf2f(u16 h) {
    union { unsigned u; float f; } un; un.u = ((unsigned)h) << 16; return un.f;
}
__device__ __forceinline__ u16 f2bf(float f) {
    union { float f; unsigned u; } un; un.f = f;
    unsigned u = un.u;
    u += 0x7fffu + ((u >> 16) & 1u);   // RNE
    return (u16)(u >> 16);
}
// packed fp32x2 -> bf16x2 (RNE), single HW instr
__device__ __forceinline__ unsigned cvt_pk_bf16(float lo, float hi) {
    unsigned r;
    asm("v_cvt_pk_bf16_f32 %0, %1, %2" : "=v"(r) : "v"(lo), "v"(hi));
    return r;
}

// async global->LDS, 16B per lane, dest = wave-uniform base + lane*16
__device__ __forceinline__ void gload16(const u16* g, u16* l) {
    __builtin_amdgcn_global_load_lds(
        (const __attribute__((address_space(1))) void*)g,
        (__attribute__((address_space(3))) void*)l, 16, 0, 0);
}

#define SBAR()       asm volatile("s_barrier" ::: "memory")
#define WAIT_LGKM0() do { asm volatile("s_waitcnt lgkmcnt(0)" ::: "memory"); \
                          __builtin_amdgcn_sched_barrier(0); } while (0)
#define WAIT_VM(N)   asm volatile("s_waitcnt vmcnt(" #N ")" ::: "memory")

// ---------------------------------------------------------------------------
// Embedding kernels -> bf16
// ---------------------------------------------------------------------------
__device__ __forceinline__ float pos_enc(int pos, int c) {
    int i2 = c & ~1;
    float div = expf(-(float)i2 * (9.210340371976184f / 512.0f));
    float arg = (float)pos * div;
    return (c & 1) ? cosf(arg) : sinf(arg);
}

__global__ __launch_bounds__(256) void embed_src_kernel(
    const float* __restrict__ x, const float* __restrict__ w,
    const float* __restrict__ b, u16* __restrict__ h)
{
    int idx = blockIdx.x * 256 + threadIdx.x;
    if (idx >= B_ * S_ * D_) return;
    int c  = idx & (D_ - 1);
    int bs = idx >> 9;
    int s  = bs & (S_ - 1);
    float x0 = x[bs * 2 + 0];
    float x1 = x[bs * 2 + 1];
    h[idx] = f2bf(x0 * w[c] + x1 * w[D_ + c] + b[c] + pos_enc(s, c));
}

__global__ __launch_bounds__(256) void embed_tgt_kernel(
    const float* __restrict__ y, const float* __restrict__ w,
    const float* __restrict__ b, u16* __restrict__ d)
{
    int idx = blockIdx.x * 256 + threadIdx.x;
    if (idx >= B_ * T_ * D_) return;
    int c  = idx & (D_ - 1);
    int bt = idx >> 9;
    int t  = bt % T_;
    int bb = bt / T_;
    float tv = (t == 0) ? 0.0f : y[bb * T_ + (t - 1)];
    d[idx] = f2bf(tv * w[c] + b[c] + pos_enc(t, c));
}

// ---------------------------------------------------------------------------
// Weight convert+transpose: W[K,N] fp32 -> Wt[N,K] bf16. blockIdx.z = matrix.
// ---------------------------------------------------------------------------
__global__ __launch_bounds__(256) void wconv_kernel(
    const float* __restrict__ W, u16* __restrict__ Wt, int K, int N)
{
    __shared__ float tile[32][33];
    size_t mat = (size_t)blockIdx.z * K * N;
    const float* Wm = W + mat;
    u16* Wtm = Wt + mat;
    int n0 = blockIdx.x * 32, k0 = blockIdx.y * 32;
    int tx = threadIdx.x & 31, ty = threadIdx.x >> 5;   // ty 0..7
#pragma unroll
    for (int i = 0; i < 32; i += 8)
        tile[ty + i][tx] = Wm[(size_t)(k0 + ty + i) * N + n0 + tx];
    __syncthreads();
#pragma unroll
    for (int i = 0; i < 32; i += 8)
        Wtm[(size_t)(n0 + ty + i) * K + k0 + tx] = f2bf(tile[tx][ty + i]);
}

// ---------------------------------------------------------------------------
// bf16 MFMA GEMM: C[M,N] = act(A[M,K](lda) @ Wt[N,K]^T + bias), bf16 io,
// fp32 acc. 128x128 tile, BK=64, 256 thr (4 waves, 2x2 of 64x64 quadrants).
// M,N mult of 128; K mult of 64.  (Used only for dec cross-Q now.)
// ---------------------------------------------------------------------------
__global__ __launch_bounds__(256) void gemm_bf16_kernel(
    const u16* __restrict__ A, int lda, const u16* __restrict__ Bt,
    const float* __restrict__ bias, u16* __restrict__ C, int ldc,
    int M, int N, int K, int relu)
{
    __shared__ u16 smem[18432];
    u16* As = smem;            // halves at 0, 4096
    u16* Bs = smem + 8192;     // halves at 8192, 12288

    int tid  = threadIdx.x;
    int w    = tid >> 6;
    int lane = tid & 63;
    int m0 = blockIdx.y << 7, n0 = blockIdx.x << 7;

    int sr = w * 32 + (lane >> 2);
    int sk = (lane & 3) * 8;
    const u16* ag0 = A  + (size_t)(m0 + sr)      * lda + sk;
    const u16* ag1 = A  + (size_t)(m0 + sr + 16) * lda + sk;
    const u16* bg0 = Bt + (size_t)(n0 + sr)      * K + sk;
    const u16* bg1 = Bt + (size_t)(n0 + sr + 16) * K + sk;
    u16* al0 = As + (w * 2 + 0) * 512;
    u16* al1 = As + (w * 2 + 1) * 512;
    u16* bl0 = Bs + (w * 2 + 0) * 512;
    u16* bl1 = Bs + (w * 2 + 1) * 512;

    int wm = (w >> 1) * 64, wn = (w & 1) * 64;
    int fr = lane & 15;
    int fk = (lane >> 4) * 8;

    floatx4 acc[4][4] = {};

    for (int k0 = 0; k0 < K; k0 += 64) {
#pragma unroll
        for (int hh = 0; hh < 2; ++hh) {
            int go = k0 + hh * 32;
            int lo = hh * 4096;
            gload16(ag0 + go, al0 + lo);
            gload16(ag1 + go, al1 + lo);
            gload16(bg0 + go, bl0 + lo);
            gload16(bg1 + go, bl1 + lo);
        }
        __syncthreads();

#pragma unroll
        for (int hh = 0; hh < 2; ++hh) {
            int lo = hh * 4096;
            short8 af[4], bf[4];
#pragma unroll
            for (int i = 0; i < 4; ++i)
                af[i] = *(const short8*)&As[lo + (wm + i * 16 + fr) * 32 + fk];
#pragma unroll
            for (int j = 0; j < 4; ++j)
                bf[j] = *(const short8*)&Bs[lo + (wn + j * 16 + fr) * 32 + fk];
#pragma unroll
            for (int i = 0; i < 4; ++i)
#pragma unroll
                for (int j = 0; j < 4; ++j)
                    acc[i][j] = __builtin_amdgcn_mfma_f32_16x16x32_bf16(
                        af[i], bf[j], acc[i][j], 0, 0, 0);
        }
        __syncthreads();
    }

    u16* epi = smem + w * 4608;        // 64 rows x 72 u16 stride
    int cc = lane & 15;
    int rq = (lane >> 4) * 4;
#pragma unroll
    for (int j = 0; j < 4; ++j) {
        float bj = bias[n0 + wn + j * 16 + cc];
#pragma unroll
        for (int i = 0; i < 4; ++i) {
#pragma unroll
            for (int r = 0; r < 4; ++r) {
                float vv = acc[i][j][r] + bj;
                if (relu) vv = fmaxf(vv, 0.f);
                epi[(i * 16 + rq + r) * 72 + j * 16 + cc] = f2bf(vv);
            }
        }
    }
    __syncthreads();
#pragma unroll
    for (int t = 0; t < 8; ++t) {
        int er = t * 8 + (lane >> 3);
        int ec = (lane & 7) * 8;
        short8 vv = *(const short8*)&epi[er * 72 + ec];
        *(short8*)&C[(size_t)(m0 + wm + er) * ldc + n0 + wn + ec] = vv;
    }
}

// ---------------------------------------------------------------------------
// 256x256 8-phase bf16 GEMM (quadrant form), single barrier per phase +
// counted vmcnt (see round-5 ledger in comments). M,N mult of 256; K mult
// of 128.
// ---------------------------------------------------------------------------
#define RD_A(BUF, MH) do { \
  _Pragma("unroll") for (int i_ = 0; i_ < 4; ++i_) \
  _Pragma("unroll") for (int h_ = 0; h_ < 2; ++h_) \
    a[i_][h_] = *(const short8*)&smem[(BUF) * 16384 + \
        ((MH) * 128 + qm + i_ * 16 + fr) * 64 + cSwz[h_]]; \
} while (0)

#define RD_B(BUF, NH) do { \
  _Pragma("unroll") for (int n_ = 0; n_ < 2; ++n_) \
  _Pragma("unroll") for (int h_ = 0; h_ < 2; ++h_) \
    bb[n_][h_] = *(const short8*)&smem[32768 + (BUF) * 16384 + \
        ((NH) * 128 + qn + n_ * 16 + fr) * 64 + cSwz[h_]]; \
} while (0)

#define PH_MMA(MH, NH) do { \
  __builtin_amdgcn_s_setprio(1); \
  _Pragma("unroll") for (int i_ = 0; i_ < 4; ++i_) \
  _Pragma("unroll") for (int n_ = 0; n_ < 2; ++n_) \
  _Pragma("unroll") for (int h_ = 0; h_ < 2; ++h_) \
    acc[MH][NH][i_][n_] = __builtin_amdgcn_mfma_f32_16x16x32_bf16( \
        a[i_][h_], bb[n_][h_], acc[MH][NH][i_][n_], 0, 0, 0); \
  __builtin_amdgcn_s_setprio(0); \
} while (0)

__global__ __launch_bounds__(512, 2) void gemm256_bf16_kernel(
    const u16* __restrict__ A, int lda, const u16* __restrict__ Bt,
    const float* __restrict__ bias, u16* __restrict__ C, int ldc,
    int M, int N, int K, int relu)
{
    __shared__ __align__(128) u16 smem[65536];   // 128 KiB
    const int AB0 = 0, AB1 = 16384, BB0 = 32768, BB1 = 49152;

    int tid = threadIdx.x;
    int w = tid >> 6, lane = tid & 63;
    int fr = lane & 15, q = lane >> 4;
    int qm = (w >> 2) * 64, qn = (w & 3) * 32;   // slice inside quadrant
    int r8 = tid >> 3;
    int ksrc = (((tid & 7) ^ (r8 & 7)) << 3);    // pre-swizzled global k-off
    int cSwz[2];
    cSwz[0] = ((q ^ (fr & 7)) << 3);             // h=0: k-slot q
    cSwz[1] = (((4 | q) ^ (fr & 7)) << 3);       // h=1: k-slot 4+q

    // XCD-aware bijective block swizzle (T1)
    int nbx = gridDim.x;
    int nwg = nbx * gridDim.y;
    int flat = blockIdx.y * nbx + blockIdx.x;
    int qq = nwg >> 3, rr = nwg & 7;
    int xcd = flat & 7, sidx = flat >> 3;
    int wg = (xcd < rr ? xcd * (qq + 1) : rr * (qq + 1) + (xcd - rr) * qq) + sidx;
    int m0 = (wg / nbx) << 8, n0 = (wg % nbx) << 8;

    auto stg = [&](const u16* __restrict__ G, int ld, int row0, int bufOff,
                   int half, int gk) {
#pragma unroll
        for (int j = 0; j < 2; ++j) {
            int rl = half * 128 + j * 64 + r8;
            gload16(G + (size_t)(row0 + rl) * ld + gk + ksrc,
                    smem + bufOff + ((half * 128 + j * 64 + (w << 3)) << 6));
        }
    };

    short8 a[4][2], bb[2][2];
    floatx4 acc[2][2][4][2] = {};

    // prologue: T0 all 4 slots -> buf0; T1.Bh, T1.Ah -> buf1.
    stg(A,  lda, m0, AB0, 0, 0);    // T0.Al
    stg(A,  lda, m0, AB0, 1, 0);    // T0.Ah
    stg(Bt, K,   n0, BB0, 0, 0);    // T0.Bl
    stg(Bt, K,   n0, BB0, 1, 0);    // T0.Bh
    stg(Bt, K,   n0, BB1, 1, 64);   // T1.Bh
    stg(A,  lda, m0, AB1, 1, 64);   // T1.Ah
    WAIT_VM(4);                     // retires T0.{Al,Ah,Bl,Bh}
    SBAR();

    int NIT = K >> 7;   // 2 K-tiles (BK=64) per iteration
    for (int it = 0; it < NIT; ++it) {
        const int notlast = (it < NIT - 1);
        const int gk1 = it * 128 + 64, gk2 = gk1 + 64, gk3 = gk2 + 64;
        // P1: buf0 quad(Ml,Nh); stage T1.Al -> buf1.A.h0
        RD_A(0, 0); RD_B(0, 1);
        stg(A, lda, m0, AB1, 0, gk1);
        WAIT_LGKM0(); PH_MMA(0, 1); SBAR();
        // P2: quad(Mh,Nh); stage T1.Bl -> buf1.B.h0
        RD_A(0, 1);
        stg(Bt, K, n0, BB1, 0, gk1);
        WAIT_LGKM0(); PH_MMA(1, 1); WAIT_VM(8); SBAR();
        // P3: quad(Mh,Nl); stage T2.Bh -> buf0.B.h1
        RD_B(0, 0);
        if (notlast) stg(Bt, K, n0, BB0, 1, gk2);
        WAIT_LGKM0(); PH_MMA(1, 0); SBAR();
        // P4: quad(Ml,Nl); stage T2.Ah -> buf0.A.h1
        RD_A(0, 0);
        if (notlast) stg(A, lda, m0, AB0, 1, gk2);
        WAIT_LGKM0(); PH_MMA(0, 0);
        if (notlast) { WAIT_VM(6); } else { WAIT_VM(2); }
        SBAR();
        // P5: buf1 quad(Ml,Nh); stage T2.Al -> buf0.A.h0
        RD_A(1, 0); RD_B(1, 1);
        if (notlast) stg(A, lda, m0, AB0, 0, gk2);
        WAIT_LGKM0(); PH_MMA(0, 1); SBAR();
        // P6: quad(Mh,Nh); stage T2.Bl -> buf0.B.h0
        RD_A(1, 1);
        if (notlast) stg(Bt, K, n0, BB0, 0, gk2);
        WAIT_LGKM0(); PH_MMA(1, 1);
        if (notlast) { WAIT_VM(8); } else { WAIT_VM(0); }
        SBAR();
        // P7: quad(Mh,Nl); stage T3.Bh -> buf1.B.h1
        RD_B(1, 0);
        if (notlast) stg(Bt, K, n0, BB1, 1, gk3);
        WAIT_LGKM0(); PH_MMA(1, 0); SBAR();
        // P8: quad(Ml,Nl); stage T3.Ah -> buf1.A.h1
        RD_A(1, 0);
        if (notlast) stg(A, lda, m0, AB1, 1, gk3);
        WAIT_LGKM0(); PH_MMA(0, 0);
        if (notlast) WAIT_VM(6);
        SBAR();
    }

    // epilogue: per (mh,nh) 64x32 block, bias+relu+bf16, per-wave LDS
    // bounce (64 x 40 u16), 64B-aligned short8 stores.
    u16* epi = smem + w * 2560;
    int rq = q * 4;
#pragma unroll
    for (int mh = 0; mh < 2; ++mh) {
#pragma unroll
        for (int nh = 0; nh < 2; ++nh) {
            __syncthreads();
            int bcol = n0 + nh * 128 + qn;
            int brow = m0 + mh * 128 + qm;
#pragma unroll
            for (int n = 0; n < 2; ++n) {
                float bj = bias[bcol + n * 16 + fr];
#pragma unroll
                for (int i = 0; i < 4; ++i)
#pragma unroll
                    for (int r = 0; r < 4; ++r) {
                        float vv = acc[mh][nh][i][n][r] + bj;
                        if (relu) vv = fmaxf(vv, 0.f);
                        epi[(i * 16 + rq + r) * 40 + n * 16 + fr] = f2bf(vv);
                    }
            }
            __syncthreads();
#pragma unroll
            for (int t = 0; t < 4; ++t) {
                int er = t * 16 + (lane >> 2);
                int ec = (lane & 3) * 8;
                short8 vv = *(const short8*)&epi[er * 40 + ec];
                *(short8*)&C[(size_t)(brow + er) * ldc + bcol + ec] = vv;
            }
        }
    }
}

// ---------------------------------------------------------------------------
// FUSED GEMM + residual + LayerNorm:  h[m,:] = LN(h[m,:] + A[m,:]@Wt^T + gb)
// N fixed = 512 (full row per block -> LN in-block). Block = 64 rows x 512,
// 256 thr (4 waves x 64rows x 128cols, acc[4][8]). BK=32 double-buffered,
// LDS 72 KiB -> 2 blocks/CU (the occupancy lever gemm256 lacks). [rows][32]
// tiles: each wave's fragment read spans a contiguous 1024B window ->
// conflict-free, no swizzle; staging = 9 linear gload16/iter, counted
// vmcnt(9). Epilogue: bias -> bf16 -> LDS [64][516] -> LN (4 thr/row,
// two-pass fp32 stats, shfl-4 reduce, cvt_pk packed stores). M mult of 64.
// ---------------------------------------------------------------------------
__global__ __launch_bounds__(256, 2) void gemm_ln_kernel(
    const u16* __restrict__ A, int lda, const u16* __restrict__ Bt,
    const float* __restrict__ gbias, u16* __restrict__ h,
    const float* __restrict__ lscale, const float* __restrict__ lbias,
    int K)
{
    __shared__ u16 smem[36864];   // 2 bufs x (A 64x32=2048 + B 512x32=16384)
    int tid = threadIdx.x;
    int w = tid >> 6, lane = tid & 63;
    int fr = lane & 15, quad = lane >> 4;
    int wn = w * 128;
    int m0 = blockIdx.x * 64;
    int srow = tid >> 2, skk = (tid & 3) * 8;

    const u16* Ab = A + (size_t)(m0 + srow) * lda + skk;
    const u16* Bb = Bt + (size_t)srow * K + skk;

    auto stage = [&](int buf, int k0) {
        u16* s = smem + buf * 18432;
        gload16(Ab + k0, s + tid * 8);
#pragma unroll
        for (int t = 0; t < 8; ++t)
            gload16(Bb + (size_t)t * 64 * K + k0, s + 2048 + t * 2048 + tid * 8);
    };

    floatx4 acc[4][8] = {};
    stage(0, 0);
    int NIT = K >> 5;
    for (int it = 0; it < NIT; ++it) {
        int cur = it & 1;
        if (it + 1 < NIT) { stage(cur ^ 1, (it + 1) << 5); WAIT_VM(9); }
        else             { WAIT_VM(0); }
        __syncthreads();
        const u16* s = smem + cur * 18432;
        short8 a[4], b[8];
#pragma unroll
        for (int i = 0; i < 4; ++i)
            a[i] = *(const short8*)&s[(i * 16 + fr) * 32 + quad * 8];
#pragma unroll
        for (int j = 0; j < 8; ++j)
            b[j] = *(const short8*)&s[2048 + (wn + j * 16 + fr) * 32 + quad * 8];
#pragma unroll
        for (int i = 0; i < 4; ++i)
#pragma unroll
            for (int j = 0; j < 8; ++j)
                acc[i][j] = __builtin_amdgcn_mfma_f32_16x16x32_bf16(
                    a[i], b[j], acc[i][j], 0, 0, 0);
        __syncthreads();
    }

    // ---- bias + bf16 -> epi [64][516] (aliases dead staging buffers) ----
    u16* epi = smem;
#pragma unroll
    for (int j = 0; j < 8; ++j) {
        float bj = gbias[wn + j * 16 + fr];
#pragma unroll
        for (int i = 0; i < 4; ++i)
#pragma unroll
            for (int r = 0; r < 4; ++r)
                epi[(i * 16 + quad * 4 + r) * 516 + wn + j * 16 + fr] =
                    f2bf(acc[i][j][r] + bj);
    }
    __syncthreads();

    // ---- LN: 4 threads/row, 128 cols each, two-pass fp32 ----
    int row = tid >> 2, c0 = (tid & 3) * 128;
    const u16* er = epi + row * 516 + c0;
    u16* hr = h + (size_t)(m0 + row) * 512 + c0;
    float s1 = 0.f, s2 = 0.f;
#pragma unroll
    for (int sb = 0; sb < 16; ++sb) {
        short8 cv = *(const short8*)&er[sb * 8];
        short8 hv = *(const short8*)&hr[sb * 8];
#pragma unroll
        for (int e = 0; e < 8; ++e) {
            float v = bf2f((u16)cv[e]) + bf2f((u16)hv[e]);
            s1 += v; s2 += v * v;
        }
    }
    s1 += __shfl_xor(s1, 1, 4); s1 += __shfl_xor(s1, 2, 4);
    s2 += __shfl_xor(s2, 1, 4); s2 += __shfl_xor(s2, 2, 4);
    float mu = s1 * (1.0f / 512.0f);
    float var = s2 * (1.0f / 512.0f) - mu * mu;
    float rs = rsqrtf(var + 1e-5f);
#pragma unroll
    for (int sb = 0; sb < 16; ++sb) {
        short8 cv = *(const short8*)&er[sb * 8];
        short8 hv = *(const short8*)&hr[sb * 8];
        unsigned ow[4];
#pragma unroll
        for (int p = 0; p < 4; ++p) {
            int c = c0 + sb * 8 + p * 2;
            float va = bf2f((u16)cv[p * 2])     + bf2f((u16)hv[p * 2]);
            float vb = bf2f((u16)cv[p * 2 + 1]) + bf2f((u16)hv[p * 2 + 1]);
            float ra = (va - mu) * rs * lscale[c]     + lbias[c];
            float rb = (vb - mu) * rs * lscale[c + 1] + lbias[c + 1];
            ow[p] = cvt_pk_bf16(ra, rb);
        }
        *(uint4*)&hr[sb * 8] = make_uint4(ow[0], ow[1], ow[2], ow[3]);
    }
}

// ---------------------------------------------------------------------------
// MFMA flash attention (swapped-operand, async Q/K staging, defer-max,
// cvt_pk packing). See round-4 comments; unchanged this round.
// ---------------------------------------------------------------------------
#define CEXP 0.1803368801111244f   // 0.125 * log2(e)

__global__ __launch_bounds__(256) void attn_mfma_kernel(
    const u16* Q, int qs, const u16* __restrict__ K, int ks,
    const u16* __restrict__ V, u16* O,
    int Sq, int Sk, int causal)
{
    __shared__ u16 Qs[4096];         // [64][64] swizzled linear
    __shared__ u16 Ks[4096];         // [64][64] swizzled linear
    __shared__ u16 Vt[64 * 72];      // [d][(k + (d&~7)) & 63] (rotated cols)
    __shared__ u16 Ps[4][16 * 72];   // per-wave P tile [q][key]

    int tid  = threadIdx.x;
    int w    = tid >> 6;
    int lane = tid & 63;
    int n    = lane & 15;
    int quad = lane >> 4;
    int bh = blockIdx.x;
    int bb = bh >> 3, hhd = bh & 7;
    int q0 = blockIdx.y * 64;

    const u16* Qb = Q + (size_t)bb * Sq * qs + hhd * DH_;
    const u16* Kb = K + (size_t)bb * Sk * ks + hhd * DH_;
    const u16* Vb = V + (size_t)bb * Sk * ks + hhd * DH_;

    int sr = tid >> 3;                      // 0..31
    int gk = (((tid & 7) ^ (sr & 7)) << 3); // (sr+32)&7 == sr&7

    // ---- stage Q once (async) ----
    gload16(Qb + (size_t)(q0 + sr) * qs + gk, Qs + tid * 8);
    gload16(Qb + (size_t)(q0 + 32 + sr) * qs + gk, Qs + 2048 + tid * 8);

    float m_i = -1e30f, l_i = 0.f;
    floatx4 o_acc[4] = {};
    int qg = q0 + w * 16 + n;              // this lane's q-row
    int kend = causal ? ((Sk < q0 + 64) ? Sk : (q0 + 64)) : Sk;

    int csw0 = ((quad ^ (n & 7)) << 3);
    int csw1 = (((4 | quad) ^ (n & 7)) << 3);

    __syncthreads();

    short8 aq0 = *(const short8*)&Qs[(w * 16 + n) * 64 + csw0];
    short8 aq1 = *(const short8*)&Qs[(w * 16 + n) * 64 + csw1];

    for (int k0 = 0; k0 < kend; k0 += 64) {
        // ---- stage K (async, swizzled) ----
        gload16(Kb + (size_t)(k0 + sr) * ks + gk, Ks + tid * 8);
        gload16(Kb + (size_t)(k0 + 32 + sr) * ks + gk, Ks + 2048 + tid * 8);
        // ---- stage V (reg, transposed + rotated cols) ----
#pragma unroll
        for (int it = 0; it < 2; ++it) {
            int idx = it * 256 + tid;
            int r = idx >> 3, dg = (idx & 7) * 8;
            short8 vv = *(const short8*)&Vb[(size_t)(k0 + r) * ks + dg];
            int col = (r + dg) & 63;       // rotation by dg = d & ~7
#pragma unroll
            for (int j = 0; j < 8; ++j)
                Vt[(dg + j) * 72 + col] = (u16)vv[j];
        }
        __syncthreads();

        // ---- swapped QK^T: mfma(K,Q) -> sc[j][r] = S[k0+16j+4quad+r][qg]
        floatx4 sc[4] = {};
#pragma unroll
        for (int j = 0; j < 4; ++j) {
            short8 bk0 = *(const short8*)&Ks[(j * 16 + n) * 64 + csw0];
            short8 bk1 = *(const short8*)&Ks[(j * 16 + n) * 64 + csw1];
            sc[j] = __builtin_amdgcn_mfma_f32_16x16x32_bf16(bk0, aq0, sc[j], 0, 0, 0);
            sc[j] = __builtin_amdgcn_mfma_f32_16x16x32_bf16(bk1, aq1, sc[j], 0, 0, 0);
        }

        bool need_mask = (k0 + 64 > Sk) ||
                         (causal && (k0 + 63 > q0 + w * 16));
        if (need_mask) {
#pragma unroll
            for (int j = 0; j < 4; ++j) {
#pragma unroll
                for (int r = 0; r < 4; ++r) {
                    int kg = k0 + j * 16 + quad * 4 + r;
                    if (kg >= Sk || (causal && kg > qg))
                        sc[j][r] = -1e30f;
                }
            }
        }

        // ---- lane-local online softmax with defer-max (T13) ----
        float mx = sc[0][0];
#pragma unroll
        for (int j = 0; j < 4; ++j)
#pragma unroll
            for (int r = 0; r < 4; ++r) mx = fmaxf(mx, sc[j][r]);
        mx = fmaxf(mx, __shfl_xor(mx, 16));
        mx = fmaxf(mx, __shfl_xor(mx, 32));
        if (__any(mx > m_i + 8.0f)) {
            float mnew = fmaxf(m_i, mx);
            float alpha = exp2f((m_i - mnew) * CEXP);
            m_i = mnew;
            l_i *= alpha;
#pragma unroll
            for (int jb = 0; jb < 4; ++jb)
#pragma unroll
                for (int r = 0; r < 4; ++r) o_acc[jb][r] *= alpha;
        }
        float ps = 0.f;
#pragma unroll
        for (int j = 0; j < 4; ++j)
#pragma unroll
            for (int r = 0; r < 4; ++r) {
                float p = exp2f((sc[j][r] - m_i) * CEXP);
                sc[j][r] = p; ps += p;
            }
        ps += __shfl_xor(ps, 16);
        ps += __shfl_xor(ps, 32);
        l_i += ps;

        // ---- P -> per-wave LDS [q][key], HW packed bf16 ----
#pragma unroll
        for (int j = 0; j < 4; ++j) {
            unsigned p0 = cvt_pk_bf16(sc[j][0], sc[j][1]);
            unsigned p1 = cvt_pk_bf16(sc[j][2], sc[j][3]);
            *(uint2*)&Ps[w][n * 72 + j * 16 + quad * 4] = make_uint2(p0, p1);
        }

        // ---- swapped PV: mfma(V^T, P) -> o_acc[jb][r] = O[qg][16jb+4quad+r]
        short8 ap0 = *(const short8*)&Ps[w][n * 72 + quad * 8];
        short8 ap1 = *(const short8*)&Ps[w][n * 72 + 32 + quad * 8];
#pragma unroll
        for (int jb = 0; jb < 4; ++jb) {
            int d = jb * 16 + n;
            int rot = d & ~7;
            short8 bv0 = *(const short8*)&Vt[d * 72 + ((quad * 8 + rot) & 63)];
            short8 bv1 = *(const short8*)&Vt[d * 72 + ((32 + quad * 8 + rot) & 63)];
            o_acc[jb] = __builtin_amdgcn_mfma_f32_16x16x32_bf16(bv0, ap0, o_acc[jb], 0, 0, 0);
            o_acc[jb] = __builtin_amdgcn_mfma_f32_16x16x32_bf16(bv1, ap1, o_acc[jb], 0, 0, 0);
        }
        __syncthreads();
    }

    // ---- output: O[qg][d], lane-local scale, 8B vector stores ----
    float inv = 1.0f / l_i;
    u16* Ob = O + (size_t)bb * Sq * qs + hhd * DH_;
    if (qg < Sq) {
#pragma unroll
        for (int jb = 0; jb < 4; ++jb) {
            unsigned p0 = cvt_pk_bf16(o_acc[jb][0] * inv, o_acc[jb][1] * inv);
            unsigned p1 = cvt_pk_bf16(o_acc[jb][2] * inv, o_acc[jb][3] * inv);
            *(uint2*)&Ob[(size_t)qg * qs + jb * 16 + quad * 4] = make_uint2(p0, p1);
        }
    }
}

// ---------------------------------------------------------------------------
// out[row] = d[row,:] . w[:] + b   (one wave per row; d bf16, out fp32)
// ---------------------------------------------------------------------------
__global__ __launch_bounds__(64) void out_proj_kernel(
    const u16* __restrict__ d, const float* __restrict__ w,
    const float* __restrict__ b, float* __restrict__ out)
{
    int row = blockIdx.x, lane = threadIdx.x;
    float s = 0.f;
    for (int c = lane; c < D_; c += 64) s += bf2f(d[(size_t)row * D_ + c]) * w[c];
#pragma unroll
    for (int off = 32; off > 0; off >>= 1) s += __shfl_down(s, off);
    if (lane == 0) out[row] = s + b[0];
}

// ---------------------------------------------------------------------------
// Host orchestration
// ---------------------------------------------------------------------------
extern "C" void kernel_launch(void* const* d_in, const int* in_sizes, int n_in,
                              void* d_out, int out_size, void* d_ws, size_t ws_size,
                              hipStream_t stream)
{
    const float* x          = (const float*)d_in[0];
    const float* y          = (const float*)d_in[1];
    const float* src_w      = (const float*)d_in[2];
    const float* src_b      = (const float*)d_in[3];
    const float* tgt_w      = (const float*)d_in[4];
    const float* tgt_b      = (const float*)d_in[5];
    const float* enc_attn_w = (const float*)d_in[6];
    const float* enc_attn_b = (const float*)d_in[7];
    const float* enc_ffn_w1 = (const float*)d_in[8];
    const float* enc_ffn_b1 = (const float*)d_in[9];
    const float* enc_ffn_w2 = (const float*)d_in[10];
    const float* enc_ffn_b2 = (const float*)d_in[11];
    const float* enc_ln_s   = (const float*)d_in[12];
    const float* enc_ln_b   = (const float*)d_in[13];
    const float* dec_self_w = (const float*)d_in[14];
    const float* dec_self_b = (const float*)d_in[15];
    const float* dec_cross_w= (const float*)d_in[16];
    const float* dec_cross_b= (const float*)d_in[17];
    const float* dec_ffn_w1 = (const float*)d_in[18];
    const float* dec_ffn_b1 = (const float*)d_in[19];
    const float* dec_ffn_w2 = (const float*)d_in[20];
    const float* dec_ffn_b2 = (const float*)d_in[21];
    const float* dec_ln_s   = (const float*)d_in[22];
    const float* dec_ln_b   = (const float*)d_in[23];
    const float* out_w      = (const float*)d_in[24];
    const float* out_b      = (const float*)d_in[25];
    float* out = (float*)d_out;

    // Workspace (u16 elems). Layout unchanged from prior rounds.
    const size_t E_BSD = (size_t)B_ * S_ * D_;    // 8,388,608
    const size_t E_BTD = (size_t)B_ * T_ * D_;    // 2,949,120
    const size_t WDD   = (size_t)D_ * D_;         // 262,144
    const size_t WDF   = (size_t)D_ * F_;         // 1,048,576
    const int MS = B_ * S_;   // 16384
    const int MT = B_ * T_;   // 5760
    const int MTP = 5888;     // MT padded to 23*256 for gemm256

    u16* h    = (u16*)d_ws;                  // encoder state -> memory
    u16* qkv  = h + E_BSD;                   // [MS,1536] fused QKV / scratch
    u16* o    = qkv + (size_t)MS * 1536;     // (now unused; layout kept)
    u16* dbuf = o + E_BSD;                   // decoder state
    u16* wsc  = dbuf + E_BTD;                // weight scratch (10 slots max)
    u16* mid  = qkv;                         // FFN hidden (<= 8192x2048)
    u16* cq   = qkv;                         // cross-attn Q [MT,512]
    u16* ckv  = qkv + 4 * 1024 * 1024;       // cross-attn KV [MS,1024]

    auto gemm = [&](const u16* A, int lda, const u16* Wt, const float* bi,
                    u16* C, int ldc, int M, int N, int K, int relu) {
        dim3 g(N / 128, M / 128);
        gemm_bf16_kernel<<<g, dim3(256), 0, stream>>>(A, lda, Wt, bi, C, ldc,
                                                      M, N, K, relu);
    };
    auto gemm256 = [&](const u16* A, int lda, const u16* Wt, const float* bi,
                       u16* C, int ldc, int M, int N, int K, int relu) {
        dim3 g(N / 256, M / 256);
        gemm256_bf16_kernel<<<g, dim3(512), 0, stream>>>(A, lda, Wt, bi, C, ldc,
                                                         M, N, K, relu);
    };
    auto gemmln = [&](const u16* A, int lda, const u16* Wt, const float* gb,
                      u16* hp, const float* ls, const float* lb, int M, int K) {
        gemm_ln_kernel<<<dim3(M / 64), dim3(256), 0, stream>>>(
            A, lda, Wt, gb, hp, ls, lb, K);
    };
    auto attn = [&](const u16* Qp, int qs, const u16* Kp, int ks,
                    const u16* Vp, u16* Op, int Sq, int Sk, int causal) {
        dim3 g(B_ * H_, (Sq + 63) / 64);
        attn_mfma_kernel<<<g, dim3(256), 0, stream>>>(Qp, qs, Kp, ks, Vp, Op,
                                                      Sq, Sk, causal);
    };
    auto wconv = [&](const float* W, u16* Wt, int K, int N, int nmat) {
        wconv_kernel<<<dim3(N / 32, K / 32, nmat), dim3(256), 0, stream>>>(W, Wt, K, N);
    };

    // ---- encoder ----
    embed_src_kernel<<<dim3((B_ * S_ * D_ + 255) / 256), dim3(256), 0, stream>>>(
        x, src_w, src_b, h);
    for (int l = 0; l < L_; ++l) {
        wconv(enc_attn_w + (size_t)l * 4 * WDD, wsc, D_, D_, 4);   // q,k,v,o
        wconv(enc_ffn_w1 + (size_t)l * WDF, wsc + 4 * WDD, D_, F_, 1);
        wconv(enc_ffn_w2 + (size_t)l * WDF, wsc + 4 * WDD + WDF, F_, D_, 1);

        const float* bl = enc_attn_b + (size_t)l * 4 * D_;
        // fused QKV: N=1536, bias [bq|bk|bv] contiguous (256^2 8-phase)
        gemm256(h, D_, wsc, bl, qkv, 1536, MS, 1536, D_, 0);
        attn(qkv, 1536, qkv + 512, 1536, qkv + 1024, qkv, S_, S_, 0); // in-place
        // fused O-proj + residual + LN0 (updates h in place)
        gemmln(qkv, 1536, wsc + 3 * WDD, bl + 3 * D_, h,
               enc_ln_s + (size_t)l * 2 * D_, enc_ln_b + (size_t)l * 2 * D_,
               MS, D_);

        // FFN, chunked by 8192 rows (mid aliases dead qkv region);
        // FFN2 fused with residual + LN1 per chunk (row-disjoint)
        for (int m0 = 0; m0 < MS; m0 += 8192) {
            gemm256(h + (size_t)m0 * D_, D_, wsc + 4 * WDD,
                    enc_ffn_b1 + (size_t)l * F_, mid, F_, 8192, F_, D_, 1);
            gemmln(mid, F_, wsc + 4 * WDD + WDF, enc_ffn_b2 + (size_t)l * D_,
                   h + (size_t)m0 * D_,
                   enc_ln_s + (size_t)l * 2 * D_ + D_,
                   enc_ln_b + (size_t)l * 2 * D_ + D_, 8192, F_);
        }
    }
    // h == memory from here on.

    // ---- decoder ----
    embed_tgt_kernel<<<dim3((B_ * T_ * D_ + 255) / 256), dim3(256), 0, stream>>>(
        y, tgt_w, tgt_b, dbuf);
    for (int l = 0; l < L_; ++l) {
        wconv(dec_self_w  + (size_t)l * 4 * WDD, wsc, D_, D_, 4);
        wconv(dec_cross_w + (size_t)l * 4 * WDD, wsc + 4 * WDD, D_, D_, 4);
        wconv(dec_ffn_w1  + (size_t)l * WDF, wsc + 8 * WDD, D_, F_, 1);
        wconv(dec_ffn_w2  + (size_t)l * WDF, wsc + 8 * WDD + WDF, F_, D_, 1);

        // self-attention (causal), fused QKV (M padded to 5888 for 256-tile)
        const float* bl = dec_self_b + (size_t)l * 4 * D_;
        gemm256(dbuf, D_, wsc, bl, qkv, 1536, MTP, 1536, D_, 0);
        attn(qkv, 1536, qkv + 512, 1536, qkv + 1024, qkv, T_, T_, 1);
        gemmln(qkv, 1536, wsc + 3 * WDD, bl + 3 * D_, dbuf,
               dec_ln_s + (size_t)l * 3 * D_, dec_ln_b + (size_t)l * 3 * D_,
               MT, D_);

        // cross-attention: fused KV over memory, Q over decoder state
        const float* bc = dec_cross_b + (size_t)l * 4 * D_;
        gemm256(h, D_, wsc + 5 * WDD, bc + D_, ckv, 1024, MS, 1024, D_, 0);
        gemm(dbuf, D_, wsc + 4 * WDD, bc, cq, D_, MT, D_, D_, 0);
        attn(cq, 512, ckv, 1024, ckv + 512, cq, T_, S_, 0);   // in-place
        gemmln(cq, 512, wsc + 7 * WDD, bc + 3 * D_, dbuf,
               dec_ln_s + (size_t)l * 3 * D_ + D_,
               dec_ln_b + (size_t)l * 3 * D_ + D_, MT, D_);

        // FFN (FFN1 on 256-tile with padded M; FFN2 fused + LN2)
        gemm256(dbuf, D_, wsc + 8 * WDD, dec_ffn_b1 + (size_t)l * F_,
                mid, F_, MTP, F_, D_, 1);
        gemmln(mid, F_, wsc + 8 * WDD + WDF, dec_ffn_b2 + (size_t)l * D_,
               dbuf, dec_ln_s + (size_t)l * 3 * D_ + 2 * D_,
               dec_ln_b + (size_t)l * 3 * D_ + 2 * D_, MT, F_);
    }

    out_proj_kernel<<<dim3(MT), dim3(64), 0, stream>>>(dbuf, out_w, out_b, out);
}

// Round 7
// 3181.635 us; speedup vs baseline: 1.2667x; 1.2667x over previous
//
#include <hip/hip_runtime.h>
#include <math.h>

// Problem constants (TransformerController)
#define B_  32
#define S_  512
#define T_  180
#define D_  512
#define F_  2048
#define L_  6
#define H_  8
#define DH_ 64

typedef unsigned short u16;
typedef __attribute__((ext_vector_type(8))) short short8;   // 8 x bf16
typedef __attribute__((ext_vector_type(4))) float floatx4;  // MFMA acc

__device__ __forceinline__ float bf2f(u16 h) {
    union { unsigned u; float f; } un; un.u = ((unsigned)h) << 16; return un.f;
}
__device__ __forceinline__ u16 f2bf(float f) {
    union { float f; unsigned u; } un; un.f = f;
    unsigned u = un.u;
    u += 0x7fffu + ((u >> 16) & 1u);   // RNE
    return (u16)(u >> 16);
}
// packed fp32x2 -> bf16x2 (RNE), single HW instr
__device__ __forceinline__ unsigned cvt_pk_bf16(float lo, float hi) {
    unsigned r;
    asm("v_cvt_pk_bf16_f32 %0, %1, %2" : "=v"(r) : "v"(lo), "v"(hi));
    return r;
}

// async global->LDS, 16B per lane, dest = wave-uniform base + lane*16
__device__ __forceinline__ void gload16(const u16* g, u16* l) {
    __builtin_amdgcn_global_load_lds(
        (const __attribute__((address_space(1))) void*)g,
        (__attribute__((address_space(3))) void*)l, 16, 0, 0);
}

#define SBAR()       asm volatile("s_barrier" ::: "memory")
#define WAIT_LGKM0() do { asm volatile("s_waitcnt lgkmcnt(0)" ::: "memory"); \
                          __builtin_amdgcn_sched_barrier(0); } while (0)
#define WAIT_VM(N)   asm volatile("s_waitcnt vmcnt(" #N ")" ::: "memory")

// ---------------------------------------------------------------------------
// Positional-encoding table (512 x 512 f32, bit-identical to per-element
// evaluation) + embedding kernels. Table lives in the (then-dead) qkv
// workspace region; rebuilt before the decoder because the encoder
// clobbers it.
// ---------------------------------------------------------------------------
__global__ __launch_bounds__(256) void pe_build_kernel(float* __restrict__ pe)
{
    int idx = blockIdx.x * 256 + threadIdx.x;   // pos*512 + c
    int c = idx & (D_ - 1);
    int pos = idx >> 9;
    int i2 = c & ~1;
    float div = expf(-(float)i2 * (9.210340371976184f / 512.0f));
    float arg = (float)pos * div;
    pe[idx] = (c & 1) ? cosf(arg) : sinf(arg);
}

__global__ __launch_bounds__(256) void embed_src_kernel(
    const float* __restrict__ x, const float* __restrict__ w,
    const float* __restrict__ b, const float* __restrict__ pe,
    u16* __restrict__ h)
{
    int idx = blockIdx.x * 256 + threadIdx.x;
    if (idx >= B_ * S_ * D_) return;
    int c  = idx & (D_ - 1);
    int bs = idx >> 9;
    int s  = bs & (S_ - 1);
    float x0 = x[bs * 2 + 0];
    float x1 = x[bs * 2 + 1];
    h[idx] = f2bf(x0 * w[c] + x1 * w[D_ + c] + b[c] + pe[s * D_ + c]);
}

__global__ __launch_bounds__(256) void embed_tgt_kernel(
    const float* __restrict__ y, const float* __restrict__ w,
    const float* __restrict__ b, const float* __restrict__ pe,
    u16* __restrict__ d)
{
    int idx = blockIdx.x * 256 + threadIdx.x;
    if (idx >= B_ * T_ * D_) return;
    int c  = idx & (D_ - 1);
    int bt = idx >> 9;
    int t  = bt % T_;
    int bb = bt / T_;
    float tv = (t == 0) ? 0.0f : y[bb * T_ + (t - 1)];
    d[idx] = f2bf(tv * w[c] + b[c] + pe[t * D_ + c]);
}

// ---------------------------------------------------------------------------
// Weight convert+transpose: W[K,N] fp32 -> Wt[N,K] bf16. blockIdx.z = matrix.
// ---------------------------------------------------------------------------
__global__ __launch_bounds__(256) void wconv_kernel(
    const float* __restrict__ W, u16* __restrict__ Wt, int K, int N)
{
    __shared__ float tile[32][33];
    size_t mat = (size_t)blockIdx.z * K * N;
    const float* Wm = W + mat;
    u16* Wtm = Wt + mat;
    int n0 = blockIdx.x * 32, k0 = blockIdx.y * 32;
    int tx = threadIdx.x & 31, ty = threadIdx.x >> 5;   // ty 0..7
#pragma unroll
    for (int i = 0; i < 32; i += 8)
        tile[ty + i][tx] = Wm[(size_t)(k0 + ty + i) * N + n0 + tx];
    __syncthreads();
#pragma unroll
    for (int i = 0; i < 32; i += 8)
        Wtm[(size_t)(n0 + ty + i) * K + k0 + tx] = f2bf(tile[tx][ty + i]);
}

// ---------------------------------------------------------------------------
// bf16 MFMA GEMM: C[M,N] = act(A[M,K](lda) @ Wt[N,K]^T + bias), bf16 io,
// fp32 acc. 128x128 tile, BK=64 (two 32-halves per barrier pair), 256 thr
// (4 waves, 2x2 of 64x64 quadrants). M,N mult of 128; K mult of 64.
// ---------------------------------------------------------------------------
__global__ __launch_bounds__(256) void gemm_bf16_kernel(
    const u16* __restrict__ A, int lda, const u16* __restrict__ Bt,
    const float* __restrict__ bias, u16* __restrict__ C, int ldc,
    int M, int N, int K, int relu)
{
    // As/Bs: 2 halves x (128 rows x 32 k) = 8192 u16 each. epi aliases all.
    __shared__ u16 smem[18432];
    u16* As = smem;            // halves at 0, 4096
    u16* Bs = smem + 8192;     // halves at 8192, 12288

    int tid  = threadIdx.x;
    int w    = tid >> 6;
    int lane = tid & 63;
    int m0 = blockIdx.y << 7, n0 = blockIdx.x << 7;

    // staging: per half, per wave 2 instrs A + 2 instrs B; 16 rows/instr
    int sr = w * 32 + (lane >> 2);
    int sk = (lane & 3) * 8;
    const u16* ag0 = A  + (size_t)(m0 + sr)      * lda + sk;
    const u16* ag1 = A  + (size_t)(m0 + sr + 16) * lda + sk;
    const u16* bg0 = Bt + (size_t)(n0 + sr)      * K + sk;
    const u16* bg1 = Bt + (size_t)(n0 + sr + 16) * K + sk;
    u16* al0 = As + (w * 2 + 0) * 512;
    u16* al1 = As + (w * 2 + 1) * 512;
    u16* bl0 = Bs + (w * 2 + 0) * 512;
    u16* bl1 = Bs + (w * 2 + 1) * 512;

    int wm = (w >> 1) * 64, wn = (w & 1) * 64;
    int fr = lane & 15;
    int fk = (lane >> 4) * 8;

    floatx4 acc[4][4] = {};

    for (int k0 = 0; k0 < K; k0 += 64) {
#pragma unroll
        for (int hh = 0; hh < 2; ++hh) {
            int go = k0 + hh * 32;
            int lo = hh * 4096;
            gload16(ag0 + go, al0 + lo);
            gload16(ag1 + go, al1 + lo);
            gload16(bg0 + go, bl0 + lo);
            gload16(bg1 + go, bl1 + lo);
        }
        __syncthreads();

#pragma unroll
        for (int hh = 0; hh < 2; ++hh) {
            int lo = hh * 4096;
            short8 af[4], bf[4];
#pragma unroll
            for (int i = 0; i < 4; ++i)
                af[i] = *(const short8*)&As[lo + (wm + i * 16 + fr) * 32 + fk];
#pragma unroll
            for (int j = 0; j < 4; ++j)
                bf[j] = *(const short8*)&Bs[lo + (wn + j * 16 + fr) * 32 + fk];
#pragma unroll
            for (int i = 0; i < 4; ++i)
#pragma unroll
                for (int j = 0; j < 4; ++j)
                    acc[i][j] = __builtin_amdgcn_mfma_f32_16x16x32_bf16(
                        af[i], bf[j], acc[i][j], 0, 0, 0);
        }
        __syncthreads();
    }

    // epilogue: bias+relu+bf16, bounce through LDS for coalesced stores.
    // C/D frag layout: col=lane&15, row=(lane>>4)*4+reg
    u16* epi = smem + w * 4608;        // 64 rows x 72 u16 stride
    int cc = lane & 15;
    int rq = (lane >> 4) * 4;
#pragma unroll
    for (int j = 0; j < 4; ++j) {
        float bj = bias[n0 + wn + j * 16 + cc];
#pragma unroll
        for (int i = 0; i < 4; ++i) {
#pragma unroll
            for (int r = 0; r < 4; ++r) {
                float vv = acc[i][j][r] + bj;
                if (relu) vv = fmaxf(vv, 0.f);
                epi[(i * 16 + rq + r) * 72 + j * 16 + cc] = f2bf(vv);
            }
        }
    }
    __syncthreads();
#pragma unroll
    for (int t = 0; t < 8; ++t) {
        int er = t * 8 + (lane >> 3);
        int ec = (lane & 7) * 8;
        short8 vv = *(const short8*)&epi[er * 72 + ec];
        *(short8*)&C[(size_t)(m0 + wm + er) * ldc + n0 + wn + ec] = vv;
    }
}

// ---------------------------------------------------------------------------
// 256x256 8-phase bf16 GEMM (quadrant form), single barrier per phase +
// counted vmcnt (ledger in round-5 notes). M,N mult of 256; K mult of 128.
// ---------------------------------------------------------------------------
#define RD_A(BUF, MH) do { \
  _Pragma("unroll") for (int i_ = 0; i_ < 4; ++i_) \
  _Pragma("unroll") for (int h_ = 0; h_ < 2; ++h_) \
    a[i_][h_] = *(const short8*)&smem[(BUF) * 16384 + \
        ((MH) * 128 + qm + i_ * 16 + fr) * 64 + cSwz[h_]]; \
} while (0)

#define RD_B(BUF, NH) do { \
  _Pragma("unroll") for (int n_ = 0; n_ < 2; ++n_) \
  _Pragma("unroll") for (int h_ = 0; h_ < 2; ++h_) \
    bb[n_][h_] = *(const short8*)&smem[32768 + (BUF) * 16384 + \
        ((NH) * 128 + qn + n_ * 16 + fr) * 64 + cSwz[h_]]; \
} while (0)

#define PH_MMA(MH, NH) do { \
  __builtin_amdgcn_s_setprio(1); \
  _Pragma("unroll") for (int i_ = 0; i_ < 4; ++i_) \
  _Pragma("unroll") for (int n_ = 0; n_ < 2; ++n_) \
  _Pragma("unroll") for (int h_ = 0; h_ < 2; ++h_) \
    acc[MH][NH][i_][n_] = __builtin_amdgcn_mfma_f32_16x16x32_bf16( \
        a[i_][h_], bb[n_][h_], acc[MH][NH][i_][n_], 0, 0, 0); \
  __builtin_amdgcn_s_setprio(0); \
} while (0)

__global__ __launch_bounds__(512, 2) void gemm256_bf16_kernel(
    const u16* __restrict__ A, int lda, const u16* __restrict__ Bt,
    const float* __restrict__ bias, u16* __restrict__ C, int ldc,
    int M, int N, int K, int relu)
{
    __shared__ __align__(128) u16 smem[65536];   // 128 KiB
    const int AB0 = 0, AB1 = 16384, BB0 = 32768, BB1 = 49152;

    int tid = threadIdx.x;
    int w = tid >> 6, lane = tid & 63;
    int fr = lane & 15, q = lane >> 4;
    int qm = (w >> 2) * 64, qn = (w & 3) * 32;   // slice inside quadrant
    int r8 = tid >> 3;
    int ksrc = (((tid & 7) ^ (r8 & 7)) << 3);    // pre-swizzled global k-off
    int cSwz[2];
    cSwz[0] = ((q ^ (fr & 7)) << 3);             // h=0: k-slot q
    cSwz[1] = (((4 | q) ^ (fr & 7)) << 3);       // h=1: k-slot 4+q

    // XCD-aware bijective block swizzle (T1)
    int nbx = gridDim.x;
    int nwg = nbx * gridDim.y;
    int flat = blockIdx.y * nbx + blockIdx.x;
    int qq = nwg >> 3, rr = nwg & 7;
    int xcd = flat & 7, sidx = flat >> 3;
    int wg = (xcd < rr ? xcd * (qq + 1) : rr * (qq + 1) + (xcd - rr) * qq) + sidx;
    int m0 = (wg / nbx) << 8, n0 = (wg % nbx) << 8;

    auto stg = [&](const u16* __restrict__ G, int ld, int row0, int bufOff,
                   int half, int gk) {
#pragma unroll
        for (int j = 0; j < 2; ++j) {
            int rl = half * 128 + j * 64 + r8;
            gload16(G + (size_t)(row0 + rl) * ld + gk + ksrc,
                    smem + bufOff + ((half * 128 + j * 64 + (w << 3)) << 6));
        }
    };

    short8 a[4][2], bb[2][2];
    floatx4 acc[2][2][4][2] = {};

    // prologue: T0 all 4 slots -> buf0; T1.Bh, T1.Ah -> buf1.
    stg(A,  lda, m0, AB0, 0, 0);    // T0.Al
    stg(A,  lda, m0, AB0, 1, 0);    // T0.Ah
    stg(Bt, K,   n0, BB0, 0, 0);    // T0.Bl
    stg(Bt, K,   n0, BB0, 1, 0);    // T0.Bh
    stg(Bt, K,   n0, BB1, 1, 64);   // T1.Bh
    stg(A,  lda, m0, AB1, 1, 64);   // T1.Ah
    WAIT_VM(4);                     // retires T0.{Al,Ah,Bl,Bh}
    SBAR();

    int NIT = K >> 7;   // 2 K-tiles (BK=64) per iteration
    for (int it = 0; it < NIT; ++it) {
        const int notlast = (it < NIT - 1);
        const int gk1 = it * 128 + 64, gk2 = gk1 + 64, gk3 = gk2 + 64;
        // P1: buf0 quad(Ml,Nh); stage T1.Al -> buf1.A.h0
        RD_A(0, 0); RD_B(0, 1);
        stg(A, lda, m0, AB1, 0, gk1);
        WAIT_LGKM0(); PH_MMA(0, 1); SBAR();
        // P2: quad(Mh,Nh); stage T1.Bl -> buf1.B.h0
        RD_A(0, 1);
        stg(Bt, K, n0, BB1, 0, gk1);
        WAIT_LGKM0(); PH_MMA(1, 1); WAIT_VM(8); SBAR();
        // P3: quad(Mh,Nl); stage T2.Bh -> buf0.B.h1
        RD_B(0, 0);
        if (notlast) stg(Bt, K, n0, BB0, 1, gk2);
        WAIT_LGKM0(); PH_MMA(1, 0); SBAR();
        // P4: quad(Ml,Nl); stage T2.Ah -> buf0.A.h1
        RD_A(0, 0);
        if (notlast) stg(A, lda, m0, AB0, 1, gk2);
        WAIT_LGKM0(); PH_MMA(0, 0);
        if (notlast) { WAIT_VM(6); } else { WAIT_VM(2); }
        SBAR();
        // P5: buf1 quad(Ml,Nh); stage T2.Al -> buf0.A.h0
        RD_A(1, 0); RD_B(1, 1);
        if (notlast) stg(A, lda, m0, AB0, 0, gk2);
        WAIT_LGKM0(); PH_MMA(0, 1); SBAR();
        // P6: quad(Mh,Nh); stage T2.Bl -> buf0.B.h0
        RD_A(1, 1);
        if (notlast) stg(Bt, K, n0, BB0, 0, gk2);
        WAIT_LGKM0(); PH_MMA(1, 1);
        if (notlast) { WAIT_VM(8); } else { WAIT_VM(0); }
        SBAR();
        // P7: quad(Mh,Nl); stage T3.Bh -> buf1.B.h1
        RD_B(1, 0);
        if (notlast) stg(Bt, K, n0, BB1, 1, gk3);
        WAIT_LGKM0(); PH_MMA(1, 0); SBAR();
        // P8: quad(Ml,Nl); stage T3.Ah -> buf1.A.h1
        RD_A(1, 0);
        if (notlast) stg(A, lda, m0, AB1, 1, gk3);
        WAIT_LGKM0(); PH_MMA(0, 0);
        if (notlast) WAIT_VM(6);
        SBAR();
    }

    // epilogue: per (mh,nh) 64x32 block, bias+relu+bf16, per-wave LDS
    // bounce (64 x 40 u16), 64B-aligned short8 stores.
    u16* epi = smem + w * 2560;
    int rq = q * 4;
#pragma unroll
    for (int mh = 0; mh < 2; ++mh) {
#pragma unroll
        for (int nh = 0; nh < 2; ++nh) {
            __syncthreads();
            int bcol = n0 + nh * 128 + qn;
            int brow = m0 + mh * 128 + qm;
#pragma unroll
            for (int n = 0; n < 2; ++n) {
                float bj = bias[bcol + n * 16 + fr];
#pragma unroll
                for (int i = 0; i < 4; ++i)
#pragma unroll
                    for (int r = 0; r < 4; ++r) {
                        float vv = acc[mh][nh][i][n][r] + bj;
                        if (relu) vv = fmaxf(vv, 0.f);
                        epi[(i * 16 + rq + r) * 40 + n * 16 + fr] = f2bf(vv);
                    }
            }
            __syncthreads();
#pragma unroll
            for (int t = 0; t < 4; ++t) {
                int er = t * 16 + (lane >> 2);
                int ec = (lane & 3) * 8;
                short8 vv = *(const short8*)&epi[er * 40 + ec];
                *(short8*)&C[(size_t)(brow + er) * ldc + bcol + ec] = vv;
            }
        }
    }
}

// ---------------------------------------------------------------------------
// MFMA flash attention (swapped-operand, async Q/K staging, defer-max,
// cvt_pk packing). See round-4 comments; unchanged.
// ---------------------------------------------------------------------------
#define CEXP 0.1803368801111244f   // 0.125 * log2(e)

__global__ __launch_bounds__(256) void attn_mfma_kernel(
    const u16* Q, int qs, const u16* __restrict__ K, int ks,
    const u16* __restrict__ V, u16* O,
    int Sq, int Sk, int causal)
{
    __shared__ u16 Qs[4096];         // [64][64] swizzled linear
    __shared__ u16 Ks[4096];         // [64][64] swizzled linear
    __shared__ u16 Vt[64 * 72];      // [d][(k + (d&~7)) & 63] (rotated cols)
    __shared__ u16 Ps[4][16 * 72];   // per-wave P tile [q][key]

    int tid  = threadIdx.x;
    int w    = tid >> 6;
    int lane = tid & 63;
    int n    = lane & 15;
    int quad = lane >> 4;
    int bh = blockIdx.x;
    int bb = bh >> 3, hhd = bh & 7;
    int q0 = blockIdx.y * 64;

    const u16* Qb = Q + (size_t)bb * Sq * qs + hhd * DH_;
    const u16* Kb = K + (size_t)bb * Sk * ks + hhd * DH_;
    const u16* Vb = V + (size_t)bb * Sk * ks + hhd * DH_;

    int sr = tid >> 3;                      // 0..31
    int gk = (((tid & 7) ^ (sr & 7)) << 3); // (sr+32)&7 == sr&7

    // ---- stage Q once (async) ----
    gload16(Qb + (size_t)(q0 + sr) * qs + gk, Qs + tid * 8);
    gload16(Qb + (size_t)(q0 + 32 + sr) * qs + gk, Qs + 2048 + tid * 8);

    float m_i = -1e30f, l_i = 0.f;
    floatx4 o_acc[4] = {};
    int qg = q0 + w * 16 + n;              // this lane's q-row
    int kend = causal ? ((Sk < q0 + 64) ? Sk : (q0 + 64)) : Sk;

    int csw0 = ((quad ^ (n & 7)) << 3);
    int csw1 = (((4 | quad) ^ (n & 7)) << 3);

    __syncthreads();

    short8 aq0 = *(const short8*)&Qs[(w * 16 + n) * 64 + csw0];
    short8 aq1 = *(const short8*)&Qs[(w * 16 + n) * 64 + csw1];

    for (int k0 = 0; k0 < kend; k0 += 64) {
        // ---- stage K (async, swizzled) ----
        gload16(Kb + (size_t)(k0 + sr) * ks + gk, Ks + tid * 8);
        gload16(Kb + (size_t)(k0 + 32 + sr) * ks + gk, Ks + 2048 + tid * 8);
        // ---- stage V (reg, transposed + rotated cols) ----
#pragma unroll
        for (int it = 0; it < 2; ++it) {
            int idx = it * 256 + tid;
            int r = idx >> 3, dg = (idx & 7) * 8;
            short8 vv = *(const short8*)&Vb[(size_t)(k0 + r) * ks + dg];
            int col = (r + dg) & 63;       // rotation by dg = d & ~7
#pragma unroll
            for (int j = 0; j < 8; ++j)
                Vt[(dg + j) * 72 + col] = (u16)vv[j];
        }
        __syncthreads();

        // ---- swapped QK^T: mfma(K,Q) -> sc[j][r] = S[k0+16j+4quad+r][qg]
        floatx4 sc[4] = {};
#pragma unroll
        for (int j = 0; j < 4; ++j) {
            short8 bk0 = *(const short8*)&Ks[(j * 16 + n) * 64 + csw0];
            short8 bk1 = *(const short8*)&Ks[(j * 16 + n) * 64 + csw1];
            sc[j] = __builtin_amdgcn_mfma_f32_16x16x32_bf16(bk0, aq0, sc[j], 0, 0, 0);
            sc[j] = __builtin_amdgcn_mfma_f32_16x16x32_bf16(bk1, aq1, sc[j], 0, 0, 0);
        }

        bool need_mask = (k0 + 64 > Sk) ||
                         (causal && (k0 + 63 > q0 + w * 16));
        if (need_mask) {
#pragma unroll
            for (int j = 0; j < 4; ++j) {
#pragma unroll
                for (int r = 0; r < 4; ++r) {
                    int kg = k0 + j * 16 + quad * 4 + r;
                    if (kg >= Sk || (causal && kg > qg))
                        sc[j][r] = -1e30f;
                }
            }
        }

        // ---- lane-local online softmax with defer-max (T13) ----
        float mx = sc[0][0];
#pragma unroll
        for (int j = 0; j < 4; ++j)
#pragma unroll
            for (int r = 0; r < 4; ++r) mx = fmaxf(mx, sc[j][r]);
        mx = fmaxf(mx, __shfl_xor(mx, 16));
        mx = fmaxf(mx, __shfl_xor(mx, 32));
        if (__any(mx > m_i + 8.0f)) {
            float mnew = fmaxf(m_i, mx);
            float alpha = exp2f((m_i - mnew) * CEXP);
            m_i = mnew;
            l_i *= alpha;
#pragma unroll
            for (int jb = 0; jb < 4; ++jb)
#pragma unroll
                for (int r = 0; r < 4; ++r) o_acc[jb][r] *= alpha;
        }
        float ps = 0.f;
#pragma unroll
        for (int j = 0; j < 4; ++j)
#pragma unroll
            for (int r = 0; r < 4; ++r) {
                float p = exp2f((sc[j][r] - m_i) * CEXP);
                sc[j][r] = p; ps += p;
            }
        ps += __shfl_xor(ps, 16);
        ps += __shfl_xor(ps, 32);
        l_i += ps;

        // ---- P -> per-wave LDS [q][key], HW packed bf16 ----
#pragma unroll
        for (int j = 0; j < 4; ++j) {
            unsigned p0 = cvt_pk_bf16(sc[j][0], sc[j][1]);
            unsigned p1 = cvt_pk_bf16(sc[j][2], sc[j][3]);
            *(uint2*)&Ps[w][n * 72 + j * 16 + quad * 4] = make_uint2(p0, p1);
        }

        // ---- swapped PV: mfma(V^T, P) -> o_acc[jb][r] = O[qg][16jb+4quad+r]
        short8 ap0 = *(const short8*)&Ps[w][n * 72 + quad * 8];
        short8 ap1 = *(const short8*)&Ps[w][n * 72 + 32 + quad * 8];
#pragma unroll
        for (int jb = 0; jb < 4; ++jb) {
            int d = jb * 16 + n;
            int rot = d & ~7;
            short8 bv0 = *(const short8*)&Vt[d * 72 + ((quad * 8 + rot) & 63)];
            short8 bv1 = *(const short8*)&Vt[d * 72 + ((32 + quad * 8 + rot) & 63)];
            o_acc[jb] = __builtin_amdgcn_mfma_f32_16x16x32_bf16(bv0, ap0, o_acc[jb], 0, 0, 0);
            o_acc[jb] = __builtin_amdgcn_mfma_f32_16x16x32_bf16(bv1, ap1, o_acc[jb], 0, 0, 0);
        }
        __syncthreads();
    }

    // ---- output: O[qg][d], lane-local scale, 8B vector stores ----
    float inv = 1.0f / l_i;
    u16* Ob = O + (size_t)bb * Sq * qs + hhd * DH_;
    if (qg < Sq) {
#pragma unroll
        for (int jb = 0; jb < 4; ++jb) {
            unsigned p0 = cvt_pk_bf16(o_acc[jb][0] * inv, o_acc[jb][1] * inv);
            unsigned p1 = cvt_pk_bf16(o_acc[jb][2] * inv, o_acc[jb][3] * inv);
            *(uint2*)&Ob[(size_t)qg * qs + jb * 16 + quad * 4] = make_uint2(p0, p1);
        }
    }
}

// ---------------------------------------------------------------------------
// h[row,:] = LN(h[row,:] + delta[row,:]) * scale + bias (bf16 io, fp32 math)
// 128 threads, single barrier (wave shfl reduction, E[x^2]-mu^2 variance).
// ---------------------------------------------------------------------------
__global__ __launch_bounds__(128) void add_ln_kernel(
    u16* __restrict__ h, const u16* __restrict__ delta,
    const float* __restrict__ scale, const float* __restrict__ bias)
{
    __shared__ float red[2][2];
    int row = blockIdx.x, tid = threadIdx.x;
    int lane = tid & 63, wv = tid >> 6;
    size_t base = (size_t)row * D_ + tid * 4;
    uint2 hv = *(const uint2*)&h[base];
    uint2 dv = *(const uint2*)&delta[base];
    float v0 = bf2f(hv.x & 0xffff) + bf2f(dv.x & 0xffff);
    float v1 = bf2f(hv.x >> 16)    + bf2f(dv.x >> 16);
    float v2 = bf2f(hv.y & 0xffff) + bf2f(dv.y & 0xffff);
    float v3 = bf2f(hv.y >> 16)    + bf2f(dv.y >> 16);

    float a  = v0 + v1 + v2 + v3;
    float b2 = v0 * v0 + v1 * v1 + v2 * v2 + v3 * v3;
#pragma unroll
    for (int off = 32; off > 0; off >>= 1) {
        a  += __shfl_xor(a, off);
        b2 += __shfl_xor(b2, off);
    }
    if (lane == 0) { red[wv][0] = a; red[wv][1] = b2; }
    __syncthreads();
    float S1 = red[0][0] + red[1][0];
    float S2 = red[0][1] + red[1][1];
    float mu = S1 * (1.0f / 512.0f);
    float var = S2 * (1.0f / 512.0f) - mu * mu;
    float rs = rsqrtf(var + 1e-5f);

    int c = tid * 4;
    float4 sc = *(const float4*)&scale[c];
    float4 bi = *(const float4*)&bias[c];
    unsigned lo = (unsigned)f2bf((v0 - mu) * rs * sc.x + bi.x) |
                  ((unsigned)f2bf((v1 - mu) * rs * sc.y + bi.y) << 16);
    unsigned hi = (unsigned)f2bf((v2 - mu) * rs * sc.z + bi.z) |
                  ((unsigned)f2bf((v3 - mu) * rs * sc.w + bi.w) << 16);
    *(uint2*)&h[base] = make_uint2(lo, hi);
}

// ---------------------------------------------------------------------------
// out[row] = d[row,:] . w[:] + b   (one wave per row; d bf16, out fp32)
// ---------------------------------------------------------------------------
__global__ __launch_bounds__(64) void out_proj_kernel(
    const u16* __restrict__ d, const float* __restrict__ w,
    const float* __restrict__ b, float* __restrict__ out)
{
    int row = blockIdx.x, lane = threadIdx.x;
    float s = 0.f;
    for (int c = lane; c < D_; c += 64) s += bf2f(d[(size_t)row * D_ + c]) * w[c];
#pragma unroll
    for (int off = 32; off > 0; off >>= 1) s += __shfl_down(s, off);
    if (lane == 0) out[row] = s + b[0];
}

// ---------------------------------------------------------------------------
// Host orchestration
// ---------------------------------------------------------------------------
extern "C" void kernel_launch(void* const* d_in, const int* in_sizes, int n_in,
                              void* d_out, int out_size, void* d_ws, size_t ws_size,
                              hipStream_t stream)
{
    const float* x          = (const float*)d_in[0];
    const float* y          = (const float*)d_in[1];
    const float* src_w      = (const float*)d_in[2];
    const float* src_b      = (const float*)d_in[3];
    const float* tgt_w      = (const float*)d_in[4];
    const float* tgt_b      = (const float*)d_in[5];
    const float* enc_attn_w = (const float*)d_in[6];
    const float* enc_attn_b = (const float*)d_in[7];
    const float* enc_ffn_w1 = (const float*)d_in[8];
    const float* enc_ffn_b1 = (const float*)d_in[9];
    const float* enc_ffn_w2 = (const float*)d_in[10];
    const float* enc_ffn_b2 = (const float*)d_in[11];
    const float* enc_ln_s   = (const float*)d_in[12];
    const float* enc_ln_b   = (const float*)d_in[13];
    const float* dec_self_w = (const float*)d_in[14];
    const float* dec_self_b = (const float*)d_in[15];
    const float* dec_cross_w= (const float*)d_in[16];
    const float* dec_cross_b= (const float*)d_in[17];
    const float* dec_ffn_w1 = (const float*)d_in[18];
    const float* dec_ffn_b1 = (const float*)d_in[19];
    const float* dec_ffn_w2 = (const float*)d_in[20];
    const float* dec_ffn_b2 = (const float*)d_in[21];
    const float* dec_ln_s   = (const float*)d_in[22];
    const float* dec_ln_b   = (const float*)d_in[23];
    const float* out_w      = (const float*)d_in[24];
    const float* out_b      = (const float*)d_in[25];
    float* out = (float*)d_out;

    // Workspace (u16 elems). Total = 49,086,464 u16 = 98.2 MB.
    const size_t E_BSD = (size_t)B_ * S_ * D_;    // 8,388,608
    const size_t E_BTD = (size_t)B_ * T_ * D_;    // 2,949,120
    const size_t WDD   = (size_t)D_ * D_;         // 262,144
    const size_t WDF   = (size_t)D_ * F_;         // 1,048,576
    const int MS = B_ * S_;   // 16384
    const int MT = B_ * T_;   // 5760
    const int MTP = 5888;     // MT padded to 23*256 for gemm256 (pad rows
                              // read finite bf16, write dead qkv region)

    u16* h    = (u16*)d_ws;                  // encoder state -> memory
    u16* qkv  = h + E_BSD;                   // [MS,1536] fused QKV / scratch
    u16* o    = qkv + (size_t)MS * 1536;     // [MS,512] proj/FFN output
    u16* dbuf = o + E_BSD;                   // decoder state
    u16* wsc  = dbuf + E_BTD;                // weight scratch (10 slots max)
    // aliases into qkv region (dead when used):
    u16* mid  = qkv;                         // FFN hidden (<= 8192x2048)
    u16* cq   = qkv;                         // cross-attn Q [MT,512]
    u16* ckv  = qkv + 4 * 1024 * 1024;       // cross-attn KV [MS,1024]
    float* pe = (float*)qkv;                 // 512x512 f32 PE table (dead-
                                             // region alias; rebuilt for dec)

    auto gemm = [&](const u16* A, int lda, const u16* Wt, const float* bi,
                    u16* C, int ldc, int M, int N, int K, int relu) {
        dim3 g(N / 128, M / 128);
        gemm_bf16_kernel<<<g, dim3(256), 0, stream>>>(A, lda, Wt, bi, C, ldc,
                                                      M, N, K, relu);
    };
    auto gemm256 = [&](const u16* A, int lda, const u16* Wt, const float* bi,
                       u16* C, int ldc, int M, int N, int K, int relu) {
        dim3 g(N / 256, M / 256);
        gemm256_bf16_kernel<<<g, dim3(512), 0, stream>>>(A, lda, Wt, bi, C, ldc,
                                                         M, N, K, relu);
    };
    auto attn = [&](const u16* Qp, int qs, const u16* Kp, int ks,
                    const u16* Vp, u16* Op, int Sq, int Sk, int causal) {
        dim3 g(B_ * H_, (Sq + 63) / 64);
        attn_mfma_kernel<<<g, dim3(256), 0, stream>>>(Qp, qs, Kp, ks, Vp, Op,
                                                      Sq, Sk, causal);
    };
    auto addln = [&](u16* hp, const u16* dp, const float* sc, const float* bi,
                     int rows) {
        add_ln_kernel<<<dim3(rows), dim3(128), 0, stream>>>(hp, dp, sc, bi);
    };
    auto wconv = [&](const float* W, u16* Wt, int K, int N, int nmat) {
        wconv_kernel<<<dim3(N / 32, K / 32, nmat), dim3(256), 0, stream>>>(W, Wt, K, N);
    };

    // ---- encoder ----
    pe_build_kernel<<<dim3(S_ * D_ / 256), dim3(256), 0, stream>>>(pe);
    embed_src_kernel<<<dim3((B_ * S_ * D_ + 255) / 256), dim3(256), 0, stream>>>(
        x, src_w, src_b, pe, h);
    for (int l = 0; l < L_; ++l) {
        wconv(enc_attn_w + (size_t)l * 4 * WDD, wsc, D_, D_, 4);   // q,k,v,o
        wconv(enc_ffn_w1 + (size_t)l * WDF, wsc + 4 * WDD, D_, F_, 1);
        wconv(enc_ffn_w2 + (size_t)l * WDF, wsc + 4 * WDD + WDF, F_, D_, 1);

        const float* bl = enc_attn_b + (size_t)l * 4 * D_;
        // fused QKV: N=1536, bias [bq|bk|bv] contiguous (256^2 8-phase)
        gemm256(h, D_, wsc, bl, qkv, 1536, MS, 1536, D_, 0);
        attn(qkv, 1536, qkv + 512, 1536, qkv + 1024, qkv, S_, S_, 0); // in-place
        gemm(qkv, 1536, wsc + 3 * WDD, bl + 3 * D_, o, D_, MS, D_, D_, 0);
        addln(h, o, enc_ln_s + (size_t)l * 2 * D_, enc_ln_b + (size_t)l * 2 * D_, MS);

        // FFN, chunked by 8192 rows (mid aliases dead qkv region)
        for (int m0 = 0; m0 < MS; m0 += 8192) {
            gemm256(h + (size_t)m0 * D_, D_, wsc + 4 * WDD,
                    enc_ffn_b1 + (size_t)l * F_, mid, F_, 8192, F_, D_, 1);
            gemm(mid, F_, wsc + 4 * WDD + WDF, enc_ffn_b2 + (size_t)l * D_,
                 o + (size_t)m0 * D_, D_, 8192, D_, F_, 0);
        }
        addln(h, o, enc_ln_s + (size_t)l * 2 * D_ + D_,
              enc_ln_b + (size_t)l * 2 * D_ + D_, MS);
    }
    // h == memory from here on.

    // ---- decoder ----
    pe_build_kernel<<<dim3(S_ * D_ / 256), dim3(256), 0, stream>>>(pe);
    embed_tgt_kernel<<<dim3((B_ * T_ * D_ + 255) / 256), dim3(256), 0, stream>>>(
        y, tgt_w, tgt_b, pe, dbuf);
    for (int l = 0; l < L_; ++l) {
        wconv(dec_self_w  + (size_t)l * 4 * WDD, wsc, D_, D_, 4);
        wconv(dec_cross_w + (size_t)l * 4 * WDD, wsc + 4 * WDD, D_, D_, 4);
        wconv(dec_ffn_w1  + (size_t)l * WDF, wsc + 8 * WDD, D_, F_, 1);
        wconv(dec_ffn_w2  + (size_t)l * WDF, wsc + 8 * WDD + WDF, F_, D_, 1);

        // self-attention (causal), fused QKV (M padded to 5888 for 256-tile)
        const float* bl = dec_self_b + (size_t)l * 4 * D_;
        gemm256(dbuf, D_, wsc, bl, qkv, 1536, MTP, 1536, D_, 0);
        attn(qkv, 1536, qkv + 512, 1536, qkv + 1024, qkv, T_, T_, 1);
        gemm(qkv, 1536, wsc + 3 * WDD, bl + 3 * D_, o, D_, MT, D_, D_, 0);
        addln(dbuf, o, dec_ln_s + (size_t)l * 3 * D_,
              dec_ln_b + (size_t)l * 3 * D_, MT);

        // cross-attention: fused KV over memory, Q over decoder state
        const float* bc = dec_cross_b + (size_t)l * 4 * D_;
        gemm256(h, D_, wsc + 5 * WDD, bc + D_, ckv, 1024, MS, 1024, D_, 0);
        gemm(dbuf, D_, wsc + 4 * WDD, bc, cq, D_, MT, D_, D_, 0);
        attn(cq, 512, ckv, 1024, ckv + 512, cq, T_, S_, 0);   // in-place
        gemm(cq, D_, wsc + 7 * WDD, bc + 3 * D_, o, D_, MT, D_, D_, 0);
        addln(dbuf, o, dec_ln_s + (size_t)l * 3 * D_ + D_,
              dec_ln_b + (size_t)l * 3 * D_ + D_, MT);

        // FFN (FFN1 on 256-tile with padded M; FFN2 stays 128-tile, N=512)
        gemm256(dbuf, D_, wsc + 8 * WDD, dec_ffn_b1 + (size_t)l * F_,
                mid, F_, MTP, F_, D_, 1);
        gemm(mid, F_, wsc + 8 * WDD + WDF, dec_ffn_b2 + (size_t)l * D_,
             o, D_, MT, D_, F_, 0);
        addln(dbuf, o, dec_ln_s + (size_t)l * 3 * D_ + 2 * D_,
              dec_ln_b + (size_t)l * 3 * D_ + 2 * D_, MT);
    }

    out_proj_kernel<<<dim3(MT), dim3(64), 0, stream>>>(dbuf, out_w, out_b, out);
}